// Round 3
// baseline (668.600 us; speedup 1.0000x reference)
//
#include <hip/hip_runtime.h>
#include <math.h>

#define TSTEPS 128
#define NFEAT 16

using f32x2 = __attribute__((ext_vector_type(2))) float;

__device__ __forceinline__ float frcp(float x){ return __builtin_amdgcn_rcpf(x); }
__device__ __forceinline__ float frsq(float x){ return __builtin_amdgcn_rsqf(x); }
__device__ __forceinline__ float rdlane(float v, int l){
    return __uint_as_float(__builtin_amdgcn_readlane(__float_as_uint(v), l));
}
__device__ __forceinline__ float bperm(int addr, float v){
    return __int_as_float(__builtin_amdgcn_ds_bpermute(addr, __float_as_int(v)));
}

__device__ __forceinline__ float sigm(float x){ return frcp(1.f + __expf(-x)); }
__device__ __forceinline__ float tanh_f(float x){ return 1.f - 2.f * frcp(__expf(2.f*x) + 1.f); }

// c = cos(atan(u)/2), s = sin(atan(u)/2); 2 transcendentals
__device__ __forceinline__ void half_cs(float u, float &c, float &s){
    float ca = frsq(1.f + u*u);          // cos(atan u)
    float x  = (1.f + ca) * 0.5f;        // cos^2(half)  in (0.5, 1]
    float t  = frsq(x);
    c = x * t;                           // sqrt(x)
    s = u * ca * 0.5f * t;               // sin/(2c)
}

// xor-shuffles within 16-lane groups: masks 1,2 via DPP (VALU pipe), 4,8 via ds_swizzle
__device__ __forceinline__ float dpp_xor1(float v){
    return __int_as_float(__builtin_amdgcn_update_dpp(0, __float_as_int(v), 0xB1, 0xF, 0xF, true));
}
__device__ __forceinline__ float dpp_xor2(float v){
    return __int_as_float(__builtin_amdgcn_update_dpp(0, __float_as_int(v), 0x4E, 0xF, 0xF, true));
}
__device__ __forceinline__ float swz_xor4(float v){
    return __int_as_float(__builtin_amdgcn_ds_swizzle(__float_as_int(v), 0x101F));
}
__device__ __forceinline__ float swz_xor8(float v){
    return __int_as_float(__builtin_amdgcn_ds_swizzle(__float_as_int(v), 0x201F));
}
template<int MASK> __device__ __forceinline__ float pshfl(float v){
    if constexpr (MASK == 1) return dpp_xor1(v);
    else if constexpr (MASK == 2) return dpp_xor2(v);
    else if constexpr (MASK == 4) return swz_xor4(v);
    else return swz_xor8(v);
}

// merged RZ*RY*RX on wire I; coeffs {Ar,Ai,Br,Bi} at byte addr ai+loff in LDS.
// v' = A*v + B*partner (complex); uses packed-f32 fma on (re,im) pairs.
template<int I>
__device__ __forceinline__ void gate_step(f32x2 &v, const float* __restrict__ gt,
                                          int ai, int loff){
    const float4 g = *(const float4*)((const char*)gt + ai + loff);
    f32x2 pv;
    pv.x = pshfl<(1 << I)>(v.x);
    pv.y = pshfl<(1 << I)>(v.y);
    f32x2 sv  = { -v.y,  v.x };     // i*v
    f32x2 spv = { -pv.y, pv.x };    // i*partner
    f32x2 n = __builtin_elementwise_fma((f32x2){g.x, g.x}, v,
              __builtin_elementwise_fma((f32x2){g.y, g.y}, sv,
              __builtin_elementwise_fma((f32x2){g.z, g.z}, pv,
                                        (f32x2){g.w, g.w} * spv)));
    v = n;
}

// circuit with layer-0 permutation pre-folded into the init state:
// gates(l=0) -> P (one bpermute) -> gates(l=1) -> probs -> WHT.
__device__ __forceinline__ float circuit(f32x2 v, const float* __restrict__ gt,
                                         int a0, int a1, int a2, int a3,
                                         int bpaddr, int m){
    gate_step<0>(v, gt, a0, 0);   gate_step<1>(v, gt, a1, 0);
    gate_step<2>(v, gt, a2, 0);   gate_step<3>(v, gt, a3, 0);
    v.x = bperm(bpaddr, v.x);
    v.y = bperm(bpaddr, v.y);
    gate_step<0>(v, gt, a0, 576); gate_step<1>(v, gt, a1, 576);
    gate_step<2>(v, gt, a2, 576); gate_step<3>(v, gt, a3, 576);
    float p = v.x*v.x + v.y*v.y;
    { float o = dpp_xor1(p); p = (m & 1) ? o - p : o + p; }
    { float o = dpp_xor2(p); p = (m & 2) ? o - p : o + p; }
    { float o = swz_xor4(p); p = (m & 4) ? o - p : o + p; }
    { float o = swz_xor8(p); p = (m & 8) ? o - p : o + p; }
    return p;   // lane (16g + 2^q) holds <Z_q> of circuit g
}

// tensor-product init state evaluated at permuted basis index pm
__device__ __forceinline__ f32x2 build_init(float cA, float sA, float cB, float sB, int pm){
    float c1v[4], s1v[4], c2v[4], s2v[4];
    #pragma unroll
    for (int q = 0; q < 4; ++q){
        c1v[q] = rdlane(cA, q); s1v[q] = rdlane(sA, q);
        c2v[q] = rdlane(cB, q); s2v[q] = rdlane(sB, q);
    }
    f32x2 v;
    {
        bool b = pm & 1;
        float t = b ? s1v[0] : c1v[0];
        v.x = t * c2v[0];
        v.y = (b ? t : -t) * s2v[0];
    }
    #pragma unroll
    for (int q = 1; q < 4; ++q){
        bool bq = (pm >> q) & 1;
        float tq = bq ? s1v[q] : c1v[q];
        float fre = tq * c2v[q];
        float fim = (bq ? tq : -tq) * s2v[q];
        f32x2 n;
        n.x = v.x*fre - v.y*fim;
        n.y = v.x*fim + v.y*fre;
        v = n;
    }
    return v;
}

__global__ void __launch_bounds__(256, 4) qlstm_kernel(
    const float* __restrict__ x, const float* __restrict__ phi,
    const float* __restrict__ Wd, const float* __restrict__ bd,
    float* __restrict__ out, int B)
{
    // gtab[(l*4+i)*36 + (k*2+bit)*4 .. +3] = {Ar,Ai,Br,Bi} of merged U=RZ*RY*RX
    // row stride 144B -> the 8 (k,bit) 16B entries of one gate span all 32 banks.
    __shared__ __align__(16) float gtab[288];
    if (threadIdx.x < 96){
        int idx = threadIdx.x;
        int i = idx & 3, l = (idx >> 2) & 1, bb = (idx >> 3) & 1, k = idx >> 4;
        const float* pp = phi + (k*2 + l)*12 + 3*i;
        float ca, sa, cb, sb, cg, sg;
        __sincosf(0.5f*pp[0], &sa, &ca);
        __sincosf(0.5f*pp[1], &sb, &cb);
        __sincosf(0.5f*pp[2], &sg, &cg);
        float Ar, Ai, Br, Bi;
        if (bb == 0){
            float m00r = cb*ca,  m00i = sb*sa;     // row0 of RY*RX
            float m01r = -sb*ca, m01i = -cb*sa;
            Ar = m00r*cg + m00i*sg;  Ai = m00i*cg - m00r*sg;   // * e^{-i g/2}
            Br = m01r*cg + m01i*sg;  Bi = m01i*cg - m01r*sg;
        } else {
            float m10r = sb*ca, m10i = -cb*sa;     // row1 of RY*RX
            float m11r = cb*ca, m11i = -sb*sa;
            Ar = m11r*cg - m11i*sg;  Ai = m11i*cg + m11r*sg;   // * e^{+i g/2}
            Br = m10r*cg - m10i*sg;  Bi = m10i*cg + m10r*sg;
        }
        float* dst = gtab + (l*4 + i)*36 + (k*2 + bb)*4;
        dst[0] = Ar; dst[1] = Ai; dst[2] = Br; dst[3] = Bi;
    }
    __syncthreads();

    const int lane = threadIdx.x & 63;
    const int b = blockIdx.x * 4 + (threadIdx.x >> 6);   // wave = batch element
    const int m = lane & 15;
    const int grp = lane >> 4;                           // circuit group (f,i,Cg,o)
    const int k2 = 4 + (grp & 1);                        // phase 2: phi[4]/phi[5]
    const int q3 = m & 3;

    // CNOT-block permutation: P^{-1}(m) (one bpermute per layer; layer0 folded into init)
    const int n0 = m & 1, n1 = (m >> 1) & 1, n2 = (m >> 2) & 1, n3 = (m >> 3) & 1;
    const int pm = (n0^n1^n2) | ((n0^n2^n3) << 1) | ((n0^n1^n3) << 2) | ((n0^n1) << 3);
    const int bpaddr = ((lane & 48) | pm) * 4;

    // gate coefficient byte addresses (layer 0; +576 for layer 1)
    const int a10 =   0 + grp*32 + ((m >> 0) & 1)*16;
    const int a11 = 144 + grp*32 + ((m >> 1) & 1)*16;
    const int a12 = 288 + grp*32 + ((m >> 2) & 1)*16;
    const int a13 = 432 + grp*32 + ((m >> 3) & 1)*16;
    const int a20 =   0 + k2*32  + ((m >> 0) & 1)*16;
    const int a21 = 144 + k2*32  + ((m >> 1) & 1)*16;
    const int a22 = 288 + k2*32  + ((m >> 2) & 1)*16;
    const int a23 = 432 + k2*32  + ((m >> 3) & 1)*16;

    // packed-gather addresses: lane m pulls <Z_{m&3}> of circuit g from lane 16g + 2^{m&3}
    const int sg  = 1 << q3;
    const int adf = (0*16 + sg) * 4;   // f (phase1) / h (phase2)
    const int adi = (1*16 + sg) * 4;   // i (phase1) / y (phase2)
    const int adC = (2*16 + sg) * 4;
    const int ado = (3*16 + sg) * 4;

    // hoisted Wd rows: lane m carries feature m (cols 0..3) + h row for m<4
    float wA0 = Wd[m*20+0], wA1 = Wd[m*20+1], wA2 = Wd[m*20+2], wA3 = Wd[m*20+3];
    float wB0 = 0.f, wB1 = 0.f, wB2 = 0.f, wB3 = 0.f;
    if (m < 4){
        wB0 = Wd[(16+m)*20+0]; wB1 = Wd[(16+m)*20+1];
        wB2 = Wd[(16+m)*20+2]; wB3 = Wd[(16+m)*20+3];
    }
    const float bdsel = bd[q3];

    float h  = 0.f;    // packed: lane m holds h[m&3]
    float cc = 0.f;    // packed: lane m holds c[m&3]

    const float* xp = x + (size_t)b * TSTEPS * NFEAT;
    float* yp = out + (size_t)b * TSTEPS * 4;

    const bool bb0 = m & 1, bb1 = m & 2;
    float xv = xp[m];
    for (int t = 0; t < TSTEPS; ++t){
        // ---- z (4 cols only): packed butterfly -> lane holds z[m&3]
        float p0 = xv*wA0 + h*wB0;
        float p1 = xv*wA1 + h*wB1;
        float p2 = xv*wA2 + h*wB2;
        float p3 = xv*wA3 + h*wB3;
        float rA = bb0 ? p1 : p0, sA0 = bb0 ? p0 : p1;
        rA += dpp_xor1(sA0);
        float rB = bb0 ? p3 : p2, sB0 = bb0 ? p2 : p3;
        rB += dpp_xor1(sB0);
        float u2 = bb1 ? rB : rA, v2 = bb1 ? rA : rB;
        u2 += dpp_xor2(v2);
        u2 += swz_xor4(u2);
        u2 += swz_xor8(u2);
        float zsel = u2 + bdsel;
        if (t + 1 < TSTEPS) xv = xp[(t+1)*NFEAT + m];

        // ---- Xf = 2*sigmoid(z)-1; packed half-angles; init state (perm-folded)
        float usel = 1.f - 2.f*frcp(__expf(zsel) + 1.f);
        float cA, sAh, cB, sBh;
        half_cs(usel, cA, sAh);
        half_cs(usel*usel, cB, sBh);
        f32x2 v = build_init(cA, sAh, cB, sBh, pm);

        // ---- phase 1: f,i,Cg,o circuits in the 4 groups
        float w1  = circuit(v, gtab, a10, a11, a12, a13, bpaddr, m);
        float w1s = sigm(w1);
        float fq = bperm(adf, w1s);
        float iq = bperm(adi, w1s);
        float Cq = bperm(adC, w1s);
        float oq = bperm(ado, w1s);

        cc = fq*cc + iq*Cq;                    // packed per-lane
        float rs = oq * tanh_f(cc);

        half_cs(rs, cA, sAh);
        half_cs(rs*rs, cB, sBh);
        f32x2 vv = build_init(cA, sAh, cB, sBh, pm);

        // ---- phase 2: h (group0, phi[4]) and y (group1, phi[5])
        float w2 = circuit(vv, gtab, a20, a21, a22, a23, bpaddr, m);
        h = bperm(adf, w2);                    // packed h[m&3]
        float yv = bperm(adi, w2);             // packed y[m&3]
        if (lane < 4) yp[t*4 + lane] = yv;
    }
    if (lane < 4){
        float* cp = out + (size_t)B*TSTEPS*4 + (size_t)b*4;
        float* hp = out + (size_t)B*TSTEPS*4 + (size_t)B*4 + (size_t)b*4;
        cp[lane] = cc;
        hp[lane] = h;
    }
}

extern "C" void kernel_launch(void* const* d_in, const int* in_sizes, int n_in,
                              void* d_out, int out_size, void* d_ws, size_t ws_size,
                              hipStream_t stream) {
    const float* x   = (const float*)d_in[0];
    const float* phi = (const float*)d_in[1];
    const float* Wd  = (const float*)d_in[2];
    const float* bd  = (const float*)d_in[3];
    float* out = (float*)d_out;
    int B = in_sizes[0] / (TSTEPS * NFEAT);   // 4096
    int blocks = (B + 3) / 4;                 // 4 waves (batch elements) per block
    hipLaunchKernelGGL(qlstm_kernel, dim3(blocks), dim3(256), 0, stream,
                       x, phi, Wd, bd, out, B);
}

// Round 4
// 324.949 us; speedup vs baseline: 2.0576x; 2.0576x over previous
//
#include <hip/hip_runtime.h>
#include <math.h>

#define TSTEPS 128
#define NFEAT 16

__device__ __forceinline__ float frcp(float x){ return __builtin_amdgcn_rcpf(x); }
__device__ __forceinline__ float frsq(float x){ return __builtin_amdgcn_rsqf(x); }
__device__ __forceinline__ float rdlane(float v, int l){
    return __uint_as_float(__builtin_amdgcn_readlane(__float_as_uint(v), l));
}
__device__ __forceinline__ float bperm(int addr, float v){
    return __int_as_float(__builtin_amdgcn_ds_bpermute(addr, __float_as_int(v)));
}

__device__ __forceinline__ float sigm(float x){ return frcp(1.f + __expf(-x)); }
__device__ __forceinline__ float tanh_f(float x){ return 1.f - 2.f * frcp(__expf(2.f*x) + 1.f); }

// c = cos(atan(u)/2), s = sin(atan(u)/2); 2 transcendentals
__device__ __forceinline__ void half_cs(float u, float &c, float &s){
    float ca = frsq(1.f + u*u);          // cos(atan u)
    float x  = (1.f + ca) * 0.5f;        // cos^2(half) in (0.5, 1]
    float t  = frsq(x);
    c = x * t;                           // sqrt(x)
    s = u * ca * 0.5f * t;               // sin/(2c)
}

// xor-shuffles within 16-lane groups: masks 1,2 via DPP (VALU pipe), 4,8 via ds_swizzle
__device__ __forceinline__ float dpp_xor1(float v){
    return __int_as_float(__builtin_amdgcn_update_dpp(0, __float_as_int(v), 0xB1, 0xF, 0xF, true));
}
__device__ __forceinline__ float dpp_xor2(float v){
    return __int_as_float(__builtin_amdgcn_update_dpp(0, __float_as_int(v), 0x4E, 0xF, 0xF, true));
}
__device__ __forceinline__ float swz_xor4(float v){
    return __int_as_float(__builtin_amdgcn_ds_swizzle(__float_as_int(v), 0x101F));
}
__device__ __forceinline__ float swz_xor8(float v){
    return __int_as_float(__builtin_amdgcn_ds_swizzle(__float_as_int(v), 0x201F));
}
template<int MASK> __device__ __forceinline__ float pshfl(float v){
    if constexpr (MASK == 1) return dpp_xor1(v);
    else if constexpr (MASK == 2) return dpp_xor2(v);
    else if constexpr (MASK == 4) return swz_xor4(v);
    else return swz_xor8(v);
}

// merged RZ*RY*RX on wire I; coeffs {Ar,Ai,Br,Bi} at byte addr ai+loff in LDS.
// scalar complex math (R2 codegen: 48 VGPR, no spills)
template<int I>
__device__ __forceinline__ void gate_step(float &re, float &im,
                                          const float* __restrict__ gt, int ai, int loff){
    const float4 g = *(const float4*)((const char*)gt + ai + loff);
    float pre = pshfl<(1 << I)>(re);
    float pim = pshfl<(1 << I)>(im);
    float nre = g.x*re - g.y*im + g.z*pre - g.w*pim;
    float nim = g.x*im + g.y*re + g.z*pim + g.w*pre;
    re = nre; im = nim;
}

// gates(l=0) -> P (one bpermute pair) -> gates(l=1) -> probs -> WHT.
// layer-0's CNOT permutation is pre-folded into the init state (pm).
__device__ __forceinline__ float circuit(float re, float im, const float* __restrict__ gt,
                                         int a0, int a1, int a2, int a3,
                                         int bpaddr, int m){
    gate_step<0>(re, im, gt, a0, 0);   gate_step<1>(re, im, gt, a1, 0);
    gate_step<2>(re, im, gt, a2, 0);   gate_step<3>(re, im, gt, a3, 0);
    re = bperm(bpaddr, re);
    im = bperm(bpaddr, im);
    gate_step<0>(re, im, gt, a0, 576); gate_step<1>(re, im, gt, a1, 576);
    gate_step<2>(re, im, gt, a2, 576); gate_step<3>(re, im, gt, a3, 576);
    float p = re*re + im*im;
    { float o = dpp_xor1(p); p = (m & 1) ? o - p : o + p; }
    { float o = dpp_xor2(p); p = (m & 2) ? o - p : o + p; }
    { float o = swz_xor4(p); p = (m & 4) ? o - p : o + p; }
    { float o = swz_xor8(p); p = (m & 8) ? o - p : o + p; }
    return p;   // lane (16g + 2^q) holds <Z_q> of circuit g
}

// tensor-product init state (RY(a1) then RZ(a2) on |0>) at permuted basis index pm
__device__ __forceinline__ void build_init(float cA, float sA, float cB, float sB,
                                           int pm, float &re, float &im){
    float c1v[4], s1v[4], c2v[4], s2v[4];
    #pragma unroll
    for (int q = 0; q < 4; ++q){
        c1v[q] = rdlane(cA, q); s1v[q] = rdlane(sA, q);
        c2v[q] = rdlane(cB, q); s2v[q] = rdlane(sB, q);
    }
    {
        bool b = pm & 1;
        float t = b ? s1v[0] : c1v[0];
        re = t * c2v[0];
        im = (b ? t : -t) * s2v[0];
    }
    #pragma unroll
    for (int q = 1; q < 4; ++q){
        bool bq = (pm >> q) & 1;
        float tq = bq ? s1v[q] : c1v[q];
        float fre = tq * c2v[q];
        float fim = (bq ? tq : -tq) * s2v[q];
        float nre = re*fre - im*fim;
        float nim = re*fim + im*fre;
        re = nre; im = nim;
    }
}

__global__ void __launch_bounds__(256, 4) qlstm_kernel(
    const float* __restrict__ x, const float* __restrict__ phi,
    const float* __restrict__ Wd, const float* __restrict__ bd,
    float* __restrict__ out, int B)
{
    // gtab[(l*4+i)*36 + (k*2+bit)*4 .. +3] = {Ar,Ai,Br,Bi} of merged U=RZ*RY*RX
    // row stride 144B -> the 8 (k,bit) 16B entries of one gate span all 32 banks.
    __shared__ __align__(16) float gtab[288];
    if (threadIdx.x < 96){
        int idx = threadIdx.x;
        int i = idx & 3, l = (idx >> 2) & 1, bb = (idx >> 3) & 1, k = idx >> 4;
        const float* pp = phi + (k*2 + l)*12 + 3*i;
        float ca, sa, cb, sb, cg, sg;
        __sincosf(0.5f*pp[0], &sa, &ca);
        __sincosf(0.5f*pp[1], &sb, &cb);
        __sincosf(0.5f*pp[2], &sg, &cg);
        float Ar, Ai, Br, Bi;
        if (bb == 0){
            float m00r = cb*ca,  m00i = sb*sa;     // row0 of RY*RX
            float m01r = -sb*ca, m01i = -cb*sa;
            Ar = m00r*cg + m00i*sg;  Ai = m00i*cg - m00r*sg;   // * e^{-i g/2}
            Br = m01r*cg + m01i*sg;  Bi = m01i*cg - m01r*sg;
        } else {
            float m10r = sb*ca, m10i = -cb*sa;     // row1 of RY*RX
            float m11r = cb*ca, m11i = -sb*sa;
            Ar = m11r*cg - m11i*sg;  Ai = m11i*cg + m11r*sg;   // * e^{+i g/2}
            Br = m10r*cg - m10i*sg;  Bi = m10i*cg + m10r*sg;
        }
        float* dst = gtab + (l*4 + i)*36 + (k*2 + bb)*4;
        dst[0] = Ar; dst[1] = Ai; dst[2] = Br; dst[3] = Bi;
    }
    __syncthreads();

    const int lane = threadIdx.x & 63;
    const int b = blockIdx.x * 4 + (threadIdx.x >> 6);   // wave = batch element
    const int m = lane & 15;
    const int grp = lane >> 4;                           // circuit group (f,i,Cg,o)
    const int k2 = 4 + (grp & 1);                        // phase 2: phi[4]/phi[5]
    const int q3 = m & 3;

    // CNOT-block permutation P^{-1}(m): one bpermute per layer (layer0 folded into init)
    const int n0 = m & 1, n1 = (m >> 1) & 1, n2 = (m >> 2) & 1, n3 = (m >> 3) & 1;
    const int pm = (n0^n1^n2) | ((n0^n2^n3) << 1) | ((n0^n1^n3) << 2) | ((n0^n1) << 3);
    const int bpaddr = ((lane & 48) | pm) * 4;

    // gate coefficient byte addresses (layer 0; +576 for layer 1)
    const int a10 =   0 + grp*32 + ((m >> 0) & 1)*16;
    const int a11 = 144 + grp*32 + ((m >> 1) & 1)*16;
    const int a12 = 288 + grp*32 + ((m >> 2) & 1)*16;
    const int a13 = 432 + grp*32 + ((m >> 3) & 1)*16;
    const int a20 =   0 + k2*32  + ((m >> 0) & 1)*16;
    const int a21 = 144 + k2*32  + ((m >> 1) & 1)*16;
    const int a22 = 288 + k2*32  + ((m >> 2) & 1)*16;
    const int a23 = 432 + k2*32  + ((m >> 3) & 1)*16;

    // packed-gather addresses: lane m pulls <Z_{m&3}> of circuit g from lane 16g + 2^{m&3}
    const int sg  = 1 << q3;
    const int adf = (0*16 + sg) * 4;   // f (phase1) / h (phase2)
    const int adi = (1*16 + sg) * 4;   // i (phase1) / y (phase2)
    const int adC = (2*16 + sg) * 4;
    const int ado = (3*16 + sg) * 4;

    // hoisted Wd rows: lane m carries feature m (cols 0..3) + h row for m<4
    float wA0 = Wd[m*20+0], wA1 = Wd[m*20+1], wA2 = Wd[m*20+2], wA3 = Wd[m*20+3];
    float wB0 = 0.f, wB1 = 0.f, wB2 = 0.f, wB3 = 0.f;
    if (m < 4){
        wB0 = Wd[(16+m)*20+0]; wB1 = Wd[(16+m)*20+1];
        wB2 = Wd[(16+m)*20+2]; wB3 = Wd[(16+m)*20+3];
    }
    const float bdsel = bd[q3];

    float h  = 0.f;    // packed: lane m holds h[m&3]
    float cc = 0.f;    // packed: lane m holds c[m&3]

    const float* xp = x + (size_t)b * TSTEPS * NFEAT;
    float* yp = out + (size_t)b * TSTEPS * 4;

    const bool bb0 = m & 1, bb1 = m & 2;
    float xv = xp[m];
    #pragma clang loop unroll(disable)
    for (int t = 0; t < TSTEPS; ++t){
        // ---- z (4 cols only): packed butterfly -> lane holds z[m&3]
        float p0 = xv*wA0 + h*wB0;
        float p1 = xv*wA1 + h*wB1;
        float p2 = xv*wA2 + h*wB2;
        float p3 = xv*wA3 + h*wB3;
        float rA = bb0 ? p1 : p0, sA0 = bb0 ? p0 : p1;
        rA += dpp_xor1(sA0);
        float rB = bb0 ? p3 : p2, sB0 = bb0 ? p2 : p3;
        rB += dpp_xor1(sB0);
        float u2 = bb1 ? rB : rA, v2 = bb1 ? rA : rB;
        u2 += dpp_xor2(v2);
        u2 += swz_xor4(u2);
        u2 += swz_xor8(u2);
        float zsel = u2 + bdsel;
        if (t + 1 < TSTEPS) xv = xp[(t+1)*NFEAT + m];

        // ---- Xf = 2*sigmoid(z)-1; packed half-angles; init state (perm-folded)
        float usel = 1.f - 2.f*frcp(__expf(zsel) + 1.f);
        float cA, sAh, cB, sBh;
        half_cs(usel, cA, sAh);
        half_cs(usel*usel, cB, sBh);
        float re, im;
        build_init(cA, sAh, cB, sBh, pm, re, im);

        // ---- phase 1: f,i,Cg,o circuits in the 4 groups
        float w1  = circuit(re, im, gtab, a10, a11, a12, a13, bpaddr, m);
        float w1s = sigm(w1);
        float fq = bperm(adf, w1s);
        float iq = bperm(adi, w1s);
        float Cq = bperm(adC, w1s);
        float oq = bperm(ado, w1s);

        cc = fq*cc + iq*Cq;                    // packed per-lane
        float rs = oq * tanh_f(cc);

        half_cs(rs, cA, sAh);
        half_cs(rs*rs, cB, sBh);
        float re2, im2;
        build_init(cA, sAh, cB, sBh, pm, re2, im2);

        // ---- phase 2: h (group0, phi[4]) and y (group1, phi[5])
        float w2 = circuit(re2, im2, gtab, a20, a21, a22, a23, bpaddr, m);
        h = bperm(adf, w2);                    // packed h[m&3]
        float yv = bperm(adi, w2);             // packed y[m&3]
        if (lane < 4) yp[t*4 + lane] = yv;
    }
    if (lane < 4){
        float* cp = out + (size_t)B*TSTEPS*4 + (size_t)b*4;
        float* hp = out + (size_t)B*TSTEPS*4 + (size_t)B*4 + (size_t)b*4;
        cp[lane] = cc;
        hp[lane] = h;
    }
}

extern "C" void kernel_launch(void* const* d_in, const int* in_sizes, int n_in,
                              void* d_out, int out_size, void* d_ws, size_t ws_size,
                              hipStream_t stream) {
    const float* x   = (const float*)d_in[0];
    const float* phi = (const float*)d_in[1];
    const float* Wd  = (const float*)d_in[2];
    const float* bd  = (const float*)d_in[3];
    float* out = (float*)d_out;
    int B = in_sizes[0] / (TSTEPS * NFEAT);   // 4096
    int blocks = (B + 3) / 4;                 // 4 waves (batch elements) per block
    hipLaunchKernelGGL(qlstm_kernel, dim3(blocks), dim3(256), 0, stream,
                       x, phi, Wd, bd, out, B);
}

// Round 5
// 271.081 us; speedup vs baseline: 2.4664x; 1.1987x over previous
//
#include <hip/hip_runtime.h>
#include <math.h>

#define TSTEPS 128
#define NFEAT 16

__device__ __forceinline__ float frcp(float x){ return __builtin_amdgcn_rcpf(x); }
__device__ __forceinline__ float frsq(float x){ return __builtin_amdgcn_rsqf(x); }
__device__ __forceinline__ float rdlane(float v, int l){
    return __uint_as_float(__builtin_amdgcn_readlane(__float_as_uint(v), l));
}
__device__ __forceinline__ float bperm(int addr, float v){
    return __int_as_float(__builtin_amdgcn_ds_bpermute(addr, __float_as_int(v)));
}

__device__ __forceinline__ float sigm(float x){ return frcp(1.f + __expf(-x)); }
__device__ __forceinline__ float tanh_f(float x){ return 1.f - 2.f * frcp(__expf(2.f*x) + 1.f); }

// c = cos(atan(u)/2), s = sin(atan(u)/2)
__device__ __forceinline__ void half_cs(float u, float &c, float &s){
    float ca = frsq(1.f + u*u);          // cos(atan u)
    float x  = (1.f + ca) * 0.5f;        // cos^2(half)
    float t  = frsq(x);
    c = x * t;                           // sqrt(x)
    s = u * ca * 0.5f * t;
}

// xor-shuffles within 16-lane groups
__device__ __forceinline__ float dpp_xor1(float v){
    return __int_as_float(__builtin_amdgcn_update_dpp(0, __float_as_int(v), 0xB1, 0xF, 0xF, true));
}
__device__ __forceinline__ float dpp_xor2(float v){
    return __int_as_float(__builtin_amdgcn_update_dpp(0, __float_as_int(v), 0x4E, 0xF, 0xF, true));
}
__device__ __forceinline__ float swz_xor4(float v){
    return __int_as_float(__builtin_amdgcn_ds_swizzle(__float_as_int(v), 0x101F));
}
__device__ __forceinline__ float swz_xor8(float v){
    return __int_as_float(__builtin_amdgcn_ds_swizzle(__float_as_int(v), 0x201F));
}
template<int MASK> __device__ __forceinline__ float pshfl(float v){
    if constexpr (MASK == 1) return dpp_xor1(v);
    else if constexpr (MASK == 2) return dpp_xor2(v);
    else if constexpr (MASK == 4) return swz_xor4(v);
    else return swz_xor8(v);
}

// merged RZ*RY*RX on wire I; coeffs {Ar,Ai,Br,Bi} at byte addr ai+loff in LDS.
template<int I>
__device__ __forceinline__ void gate_step(float &re, float &im,
                                          const float* __restrict__ gt, int ai, int loff){
    const float4 g = *(const float4*)((const char*)gt + ai + loff);
    float pre = pshfl<(1 << I)>(re);
    float pim = pshfl<(1 << I)>(im);
    float nre = g.x*re - g.y*im + g.z*pre - g.w*pim;
    float nim = g.x*im + g.y*re + g.z*pim + g.w*pre;
    re = nre; im = nim;
}

// gates(l=0) -> P (bpermute pair) -> gates(l=1) -> probs -> WHT (per 16-lane group)
__device__ __forceinline__ float circuit(float re, float im, const float* __restrict__ gt,
                                         int a0, int a1, int a2, int a3,
                                         int bpaddr, int m){
    gate_step<0>(re, im, gt, a0, 0);   gate_step<1>(re, im, gt, a1, 0);
    gate_step<2>(re, im, gt, a2, 0);   gate_step<3>(re, im, gt, a3, 0);
    re = bperm(bpaddr, re);
    im = bperm(bpaddr, im);
    gate_step<0>(re, im, gt, a0, 576); gate_step<1>(re, im, gt, a1, 576);
    gate_step<2>(re, im, gt, a2, 576); gate_step<3>(re, im, gt, a3, 576);
    float p = re*re + im*im;
    { float o = dpp_xor1(p); p = (m & 1) ? o - p : o + p; }
    { float o = dpp_xor2(p); p = (m & 2) ? o - p : o + p; }
    { float o = swz_xor4(p); p = (m & 4) ? o - p : o + p; }
    { float o = swz_xor8(p); p = (m & 8) ? o - p : o + p; }
    return p;   // lane (16g + 2^q) holds <Z_q> of circuit g
}

// tensor product over wires of selected factors, at basis index pm (explicit scalars)
__device__ __forceinline__ void init_prod(
    float c10,float c11,float c12,float c13,
    float s10,float s11,float s12,float s13,
    float c20,float c21,float c22,float c23,
    float s20,float s21,float s22,float s23,
    int pm, float &re, float &im)
{
    {
        bool b = pm & 1;
        float t = b ? s10 : c10;
        re = t * c20;
        im = (b ? t : -t) * s20;
    }
    {
        bool b = (pm >> 1) & 1;
        float t = b ? s11 : c11;
        float fre = t * c21;
        float fim = (b ? t : -t) * s21;
        float nre = re*fre - im*fim;
        float nim = re*fim + im*fre;
        re = nre; im = nim;
    }
    {
        bool b = (pm >> 2) & 1;
        float t = b ? s12 : c12;
        float fre = t * c22;
        float fim = (b ? t : -t) * s22;
        float nre = re*fre - im*fim;
        float nim = re*fim + im*fre;
        re = nre; im = nim;
    }
    {
        bool b = (pm >> 3) & 1;
        float t = b ? s13 : c13;
        float fre = t * c23;
        float fim = (b ? t : -t) * s23;
        float nre = re*fre - im*fim;
        float nim = re*fim + im*fre;
        re = nre; im = nim;
    }
}

__global__ void __launch_bounds__(256, 2) qlstm_kernel(
    const float* __restrict__ x, const float* __restrict__ phi,
    const float* __restrict__ Wd, const float* __restrict__ bd,
    float* __restrict__ out, int B)
{
    // gtab[(l*4+i)*36 + (k*2+bit)*4 .. +3] = {Ar,Ai,Br,Bi}; row stride 144B (conflict-free)
    __shared__ __align__(16) float gtab[288];
    if (threadIdx.x < 96){
        int idx = threadIdx.x;
        int i = idx & 3, l = (idx >> 2) & 1, bb = (idx >> 3) & 1, k = idx >> 4;
        const float* pp = phi + (k*2 + l)*12 + 3*i;
        float ca, sa, cb, sb, cg, sg;
        __sincosf(0.5f*pp[0], &sa, &ca);
        __sincosf(0.5f*pp[1], &sb, &cb);
        __sincosf(0.5f*pp[2], &sg, &cg);
        float Ar, Ai, Br, Bi;
        if (bb == 0){
            float m00r = cb*ca,  m00i = sb*sa;
            float m01r = -sb*ca, m01i = -cb*sa;
            Ar = m00r*cg + m00i*sg;  Ai = m00i*cg - m00r*sg;
            Br = m01r*cg + m01i*sg;  Bi = m01i*cg - m01r*sg;
        } else {
            float m10r = sb*ca, m10i = -cb*sa;
            float m11r = cb*ca, m11i = -sb*sa;
            Ar = m11r*cg - m11i*sg;  Ai = m11i*cg + m11r*sg;
            Br = m10r*cg - m10i*sg;  Bi = m10i*cg + m10r*sg;
        }
        float* dst = gtab + (l*4 + i)*36 + (k*2 + bb)*4;
        dst[0] = Ar; dst[1] = Ai; dst[2] = Br; dst[3] = Bi;
    }
    __syncthreads();

    const int lane = threadIdx.x & 63;
    const int pair = blockIdx.x * 4 + (threadIdx.x >> 6);  // wave = 2 batch elements
    const int b0 = pair * 2;
    const int eh = lane >> 5;                // 0: element b0, 1: element b0+1
    const int be = b0 + eh;
    const int m = lane & 15;
    const int grp = (lane >> 4) & 3;
    const int q3 = m & 3;
    const int k2 = 4 + (grp & 1);            // phase2: g0,g2 -> phi[4](h); g1,g3 -> phi[5](y)

    // CNOT-block permutation P^{-1}(m) (layer-0 perm folded into init)
    const int n0 = m & 1, n1 = (m >> 1) & 1, n2 = (m >> 2) & 1, n3 = (m >> 3) & 1;
    const int pm = (n0^n1^n2) | ((n0^n2^n3) << 1) | ((n0^n1^n3) << 2) | ((n0^n1) << 3);
    const int bpaddr = ((lane & 48) | pm) * 4;

    // gate coefficient byte addresses (layer 0; +576 for layer 1)
    const int a10 =   0 + grp*32 + ((m >> 0) & 1)*16;
    const int a11 = 144 + grp*32 + ((m >> 1) & 1)*16;
    const int a12 = 288 + grp*32 + ((m >> 2) & 1)*16;
    const int a13 = 432 + grp*32 + ((m >> 3) & 1)*16;
    const int a20 =   0 + k2*32  + ((m >> 0) & 1)*16;
    const int a21 = 144 + k2*32  + ((m >> 1) & 1)*16;
    const int a22 = 288 + k2*32  + ((m >> 2) & 1)*16;
    const int a23 = 432 + k2*32  + ((m >> 3) & 1)*16;

    // gathers: <Z_{m&3}> of circuit g lives at lane 16g + 2^{m&3}
    const int sg  = 1 << q3;
    const int adf = (0*16 + sg) * 4;
    const int adi = (1*16 + sg) * 4;
    const int adC = (2*16 + sg) * 4;
    const int ado = (3*16 + sg) * 4;
    const int hb  = (lane & 32) * 4;         // own-half base byte offset
    const int adh = hb + adf;                // own element's h (group 0 or 2)
    // y store gather (lanes 0..7): e=lane>>2 -> src group 1 (e0) or 3 (e1)
    const int ady = (((((lane >> 2) & 1) ? 48 : 16)) + (1 << (lane & 3))) * 4;
    // final c/h store gather (lanes 0..7)
    const int adS = ((((lane >> 2) & 1) ? 32 : 0) + (lane & 3)) * 4;

    // Wd rows: lane m carries feature m (cols 0..3) + h row for m<4
    float wA0 = Wd[m*20+0], wA1 = Wd[m*20+1], wA2 = Wd[m*20+2], wA3 = Wd[m*20+3];
    float wB0 = 0.f, wB1 = 0.f, wB2 = 0.f, wB3 = 0.f;
    if (m < 4){
        wB0 = Wd[(16+m)*20+0]; wB1 = Wd[(16+m)*20+1];
        wB2 = Wd[(16+m)*20+2]; wB3 = Wd[(16+m)*20+3];
    }
    const float bdsel = bd[q3];

    float hloc = 0.f;   // lane holds h[m&3] of its half's element
    float cc   = 0.f;   // lane holds c[m&3] of its half's element

    const float* xp = x + (size_t)be * TSTEPS * NFEAT;   // per-lane element pointer
    float* ypw = out + (size_t)(b0 + ((lane >> 2) & 1)) * TSTEPS * 4 + (lane & 3);

    const bool bb0 = m & 1, bb1 = m & 2;
    float xv = xp[m];
    #pragma clang loop unroll(disable)
    for (int t = 0; t < TSTEPS; ++t){
        // ---- z for BOTH elements (halves are group-local): lane -> z[m&3]
        float p0 = xv*wA0 + hloc*wB0;
        float p1 = xv*wA1 + hloc*wB1;
        float p2 = xv*wA2 + hloc*wB2;
        float p3 = xv*wA3 + hloc*wB3;
        float rA = bb0 ? p1 : p0, sA0 = bb0 ? p0 : p1;
        rA += dpp_xor1(sA0);
        float rB = bb0 ? p3 : p2, sB0 = bb0 ? p2 : p3;
        rB += dpp_xor1(sB0);
        float u2 = bb1 ? rB : rA, v2 = bb1 ? rA : rB;
        u2 += dpp_xor2(v2);
        u2 += swz_xor4(u2);
        u2 += swz_xor8(u2);
        float zsel = u2 + bdsel;
        if (t + 1 < TSTEPS) xv = xp[(t+1)*NFEAT + m];

        // ---- Xf + packed half-angles (once, serving both elements)
        float usel = 1.f - 2.f*frcp(__expf(zsel) + 1.f);
        float cA, sAh, cB, sBh;
        half_cs(usel, cA, sAh);
        half_cs(usel*usel, cB, sBh);

        // ---- phase-1 e0 (broadcast lanes 0..3) and e1 (lanes 32..35), full wave each
        float reA, imA, reB, imB;
        init_prod(rdlane(cA,0),rdlane(cA,1),rdlane(cA,2),rdlane(cA,3),
                  rdlane(sAh,0),rdlane(sAh,1),rdlane(sAh,2),rdlane(sAh,3),
                  rdlane(cB,0),rdlane(cB,1),rdlane(cB,2),rdlane(cB,3),
                  rdlane(sBh,0),rdlane(sBh,1),rdlane(sBh,2),rdlane(sBh,3),
                  pm, reA, imA);
        init_prod(rdlane(cA,32),rdlane(cA,33),rdlane(cA,34),rdlane(cA,35),
                  rdlane(sAh,32),rdlane(sAh,33),rdlane(sAh,34),rdlane(sAh,35),
                  rdlane(cB,32),rdlane(cB,33),rdlane(cB,34),rdlane(cB,35),
                  rdlane(sBh,32),rdlane(sBh,33),rdlane(sBh,34),rdlane(sBh,35),
                  pm, reB, imB);
        float w1a = circuit(reA, imA, gtab, a10, a11, a12, a13, bpaddr, m);
        float w1b = circuit(reB, imB, gtab, a10, a11, a12, a13, bpaddr, m);
        float sa = sigm(w1a), sb = sigm(w1b);
        float f0 = bperm(adf, sa), f1 = bperm(adf, sb);
        float i0 = bperm(adi, sa), i1 = bperm(adi, sb);
        float C0 = bperm(adC, sa), C1 = bperm(adC, sb);
        float o0 = bperm(ado, sa), o1 = bperm(ado, sb);
        float fq = eh ? f1 : f0;
        float iq = eh ? i1 : i0;
        float Cq = eh ? C1 : C0;
        float oq = eh ? o1 : o0;

        // ---- pointwise LSTM (once, both elements; group-local)
        cc = fq*cc + iq*Cq;
        float rs = oq * tanh_f(cc);
        half_cs(rs, cA, sAh);
        half_cs(rs*rs, cB, sBh);

        // ---- phase-2: within-half broadcast via bpermute, one circuit for both elements
        float re2, im2;
        init_prod(bperm(hb+0,cA), bperm(hb+4,cA), bperm(hb+8,cA), bperm(hb+12,cA),
                  bperm(hb+0,sAh),bperm(hb+4,sAh),bperm(hb+8,sAh),bperm(hb+12,sAh),
                  bperm(hb+0,cB), bperm(hb+4,cB), bperm(hb+8,cB), bperm(hb+12,cB),
                  bperm(hb+0,sBh),bperm(hb+4,sBh),bperm(hb+8,sBh),bperm(hb+12,sBh),
                  pm, re2, im2);
        float w2 = circuit(re2, im2, gtab, a20, a21, a22, a23, bpaddr, m);
        hloc = bperm(adh, w2);               // own element's h[m&3]
        float ys = bperm(ady, w2);           // store-ready y (lanes 0..7)
        if (lane < 8) ypw[t*4] = ys;
    }
    // final c, h stores (lanes 0..7 cover both elements)
    float scv = bperm(adS, cc);
    float shv = bperm(adS, hloc);
    if (lane < 8){
        int bex = b0 + ((lane >> 2) & 1);
        out[(size_t)B*TSTEPS*4 + (size_t)bex*4 + (lane & 3)] = scv;
        out[(size_t)B*TSTEPS*4 + (size_t)B*4 + (size_t)bex*4 + (lane & 3)] = shv;
    }
}

extern "C" void kernel_launch(void* const* d_in, const int* in_sizes, int n_in,
                              void* d_out, int out_size, void* d_ws, size_t ws_size,
                              hipStream_t stream) {
    const float* x   = (const float*)d_in[0];
    const float* phi = (const float*)d_in[1];
    const float* Wd  = (const float*)d_in[2];
    const float* bd  = (const float*)d_in[3];
    float* out = (float*)d_out;
    int B = in_sizes[0] / (TSTEPS * NFEAT);   // 4096
    int blocks = B / 8;                       // 4 waves/block x 2 elements/wave
    hipLaunchKernelGGL(qlstm_kernel, dim3(blocks), dim3(256), 0, stream,
                       x, phi, Wd, bd, out, B);
}

// Round 7
// 177.298 us; speedup vs baseline: 3.7711x; 1.5290x over previous
//
#include <hip/hip_runtime.h>
#include <math.h>

#define TSTEPS 128
#define NFEAT 16
#define NELEM 16   // batch elements per wave

typedef __fp16 f16;
typedef __fp16 f16x2 __attribute__((ext_vector_type(2)));
typedef __fp16 f16x8 __attribute__((ext_vector_type(8)));
typedef float f32x4 __attribute__((ext_vector_type(4)));

union F8 { f16x8 v; f16x2 h[4]; };

__device__ __forceinline__ float frcp(float x){ return __builtin_amdgcn_rcpf(x); }
__device__ __forceinline__ float frsq(float x){ return __builtin_amdgcn_rsqf(x); }
__device__ __forceinline__ float bperm(int addr, float v){
    return __int_as_float(__builtin_amdgcn_ds_bpermute(addr, __float_as_int(v)));
}
__device__ __forceinline__ f16x2 pkrtz(float a, float b){
    return __builtin_amdgcn_cvt_pkrtz(a, b);
}
__device__ __forceinline__ float swz16(float v){   // lane ^= 16 (within 32-halves)
    return __int_as_float(__builtin_amdgcn_ds_swizzle(__float_as_int(v), 0x401F));
}
__device__ __forceinline__ float dpp_xor1(float v){
    return __int_as_float(__builtin_amdgcn_update_dpp(0, __float_as_int(v), 0xB1, 0xF, 0xF, true));
}
__device__ __forceinline__ float dpp_xor2(float v){
    return __int_as_float(__builtin_amdgcn_update_dpp(0, __float_as_int(v), 0x4E, 0xF, 0xF, true));
}
__device__ __forceinline__ float swz_xor4(float v){
    return __int_as_float(__builtin_amdgcn_ds_swizzle(__float_as_int(v), 0x101F));
}
__device__ __forceinline__ float swz_xor8(float v){
    return __int_as_float(__builtin_amdgcn_ds_swizzle(__float_as_int(v), 0x201F));
}
template<int MASK> __device__ __forceinline__ float pshfl(float v){
    if constexpr (MASK == 1) return dpp_xor1(v);
    else if constexpr (MASK == 2) return dpp_xor2(v);
    else if constexpr (MASK == 4) return swz_xor4(v);
    else return swz_xor8(v);
}
__device__ __forceinline__ void cfence(){ __asm__ __volatile__("" ::: "memory"); }

__device__ __forceinline__ float sigm(float x){ return frcp(1.f + __expf(-x)); }
__device__ __forceinline__ float tanh_f(float x){ return 1.f - 2.f * frcp(__expf(2.f*x) + 1.f); }

// c = cos(atan(u)/2), s = sin(atan(u)/2)
__device__ __forceinline__ void half_cs(float u, float &c, float &s){
    float ca = frsq(1.f + u*u);
    float x  = (1.f + ca) * 0.5f;
    float t  = frsq(x);
    c = x * t;
    s = u * ca * 0.5f * t;
}

// merged RZ*RY*RX on wire I (prologue / U-construction only)
template<int I>
__device__ __forceinline__ void gate_step(float &re, float &im,
                                          const float* gt, int ai, int loff){
    const float4 g = *(const float4*)((const char*)gt + ai + loff);
    float pre = pshfl<(1 << I)>(re);
    float pim = pshfl<(1 << I)>(im);
    float nre = g.x*re - g.y*im + g.z*pre - g.w*pim;
    float nim = g.x*im + g.y*re + g.z*pim + g.w*pre;
    re = nre; im = nim;
}

// <Z_q> extraction from D_re/D_im (phi = U psi): col=lane&15=e, amp a=(lane>>4)*4+reg.
// Lane (e,s) returns ev_{q=s} of element e.
__device__ __forceinline__ float evs_own(f32x4 dre, f32x4 dim4, int addr32,
                                         bool sb0, bool sb1){
    float p0 = dre[0]*dre[0] + dim4[0]*dim4[0];
    float p1 = dre[1]*dre[1] + dim4[1]*dim4[1];
    float p2 = dre[2]*dre[2] + dim4[2]*dim4[2];
    float p3 = dre[3]*dre[3] + dim4[3]*dim4[3];
    float cp = p0 + p1, dp = p2 + p3, am = p0 - p1, bm = p2 - p3;
    float t0 = am + bm;          // (-1)^{bit0(a)} within regs
    float t1 = cp - dp;          // (-1)^{bit1(a)}
    float S  = cp + dp;
    t0 += swz16(t0);
    t1 += swz16(t1);
    float o   = swz16(S);
    float d16 = S - o, S16 = S + o;
    float p2v = sb0 ? (o - S) : d16;          // (-1)^{s&1} pair diff
    t0  += bperm(addr32, t0);                 // ev0
    t1  += bperm(addr32, t1);                 // ev1
    p2v += bperm(addr32, p2v);                // ev2
    float o2  = bperm(addr32, S16);
    float p3v = sb1 ? (o2 - S16) : (S16 - o2);// ev3
    float e01 = sb0 ? t1 : t0;
    float e23 = sb0 ? p3v : p2v;
    return sb1 ? e23 : e01;
}

// lane (e,s) emits complex factors F_s(0), F_s(1) of its wire into LDS
__device__ __forceinline__ void write_F(float* bc, int e, int s,
                                        float c1, float s1, float c2, float s2){
    float4 w;
    w.x = c1 * c2;  w.y = -(c1 * s2);    // F(0)
    w.z = s1 * c2;  w.w = s1 * s2;       // F(1)
    *(float4*)(bc + e*20 + s*4) = w;
}

// lane (e,s) builds its 4 amplitudes a=4s..4s+3 of elem e's init state (B-fragment)
__device__ __forceinline__ void build_psi(const float* bc, int e, int sm1, int sm2,
                                          F8 &bp){
    const float4 w0 = *(const float4*)(bc + e*20);               // wire0: F(0),F(1)
    const float4 w1 = *(const float4*)(bc + e*20 + 4);           // wire1
    const float2 F2 = *(const float2*)(bc + e*20 + 8  + sm1*2);  // F_2(s&1)
    const float2 F3 = *(const float2*)(bc + e*20 + 12 + sm2*2);  // F_3(s>>1)
    float pr = F2.x*F3.x - F2.y*F3.y;
    float pi = F2.x*F3.y + F2.y*F3.x;                            // prefix
    float P0r = pr*w1.x - pi*w1.y, P0i = pr*w1.y + pi*w1.x;      // prefix*F1(0)
    float P1r = pr*w1.z - pi*w1.w, P1i = pr*w1.w + pi*w1.z;      // prefix*F1(1)
    float a0r = P0r*w0.x - P0i*w0.y, a0i = P0r*w0.y + P0i*w0.x;
    float a1r = P0r*w0.z - P0i*w0.w, a1i = P0r*w0.w + P0i*w0.z;
    float a2r = P1r*w0.x - P1i*w0.y, a2i = P1r*w0.y + P1i*w0.x;
    float a3r = P1r*w0.z - P1i*w0.w, a3i = P1r*w0.w + P1i*w0.z;
    bp.h[0] = pkrtz(a0r, a0i);
    bp.h[1] = pkrtz(a1r, a1i);
    bp.h[2] = pkrtz(a2r, a2i);
    bp.h[3] = pkrtz(a3r, a3i);
}

__global__ void __launch_bounds__(64, 1) qlstm_kernel(
    const float* __restrict__ x, const float* __restrict__ phi,
    const float* __restrict__ Wd, const float* __restrict__ bd,
    float* __restrict__ out, int B)
{
    // gtab: 8 rows (l,i) x 48 floats (12 entries x {Ar,Ai,Br,Bi}) -- 192B stride
    __shared__ __align__(16) float gtab[384];
    __shared__ __align__(16) float ldsf[3776];
    const int UBo = 0;      // 3072 floats: U[k][m][c] complex at k*512+m*32+c*2
    const int BCo = 3072;   // 16 elems x 20 floats: factor pairs
    const int YBo = 3392;   // 16 elems x 20 floats: y staging (4 steps)
    const int HBo = 3712;   // 16 elems x 4 floats: h transpose

    const int tid  = threadIdx.x;
    const int lane = tid & 63;
    const int m    = lane & 15;
    const int grp  = lane >> 4;

    // ---------------- prologue: merged-gate table ------
    for (int idx = tid; idx < 96; idx += 64){
        int i = idx & 3, l = (idx >> 2) & 1, bb = (idx >> 3) & 1, k = idx >> 4;
        const float* pp = phi + (k*2 + l)*12 + 3*i;
        float ca, sa, cb, sb, cg, sg;
        __sincosf(0.5f*pp[0], &sa, &ca);
        __sincosf(0.5f*pp[1], &sb, &cb);
        __sincosf(0.5f*pp[2], &sg, &cg);
        float Ar, Ai, Br, Bi;
        if (bb == 0){
            float m00r = cb*ca,  m00i = sb*sa;
            float m01r = -sb*ca, m01i = -cb*sa;
            Ar = m00r*cg + m00i*sg;  Ai = m00i*cg - m00r*sg;
            Br = m01r*cg + m01i*sg;  Bi = m01i*cg - m01r*sg;
        } else {
            float m10r = sb*ca, m10i = -cb*sa;
            float m11r = cb*ca, m11i = -sb*sa;
            Ar = m11r*cg - m11i*sg;  Ai = m11i*cg + m11r*sg;
            Br = m10r*cg - m10i*sg;  Bi = m10i*cg + m10r*sg;
        }
        float* dst = gtab + (l*4 + i)*48 + (k*2 + bb)*4;
        dst[0] = Ar; dst[1] = Ai; dst[2] = Br; dst[3] = Bi;
    }
    __syncthreads();

    // CNOT-block permutation P^{-1}(m) and mid-circuit bpermute address
    const int n0 = m & 1, n1 = (m >> 1) & 1, n2 = (m >> 2) & 1, n3 = (m >> 3) & 1;
    const int pm = (n0^n1^n2) | ((n0^n2^n3) << 1) | ((n0^n1^n3) << 2) | ((n0^n1) << 3);
    const int bpaddr = ((lane & 48) | pm) * 4;

    // ---------------- prologue: build U_k columns via shuffle circuit --------
    for (int k = 0; k < 6; ++k){
        int ga0 = 0*192 + k*32 + ((m >> 0) & 1)*16;
        int ga1 = 1*192 + k*32 + ((m >> 1) & 1)*16;
        int ga2 = 2*192 + k*32 + ((m >> 2) & 1)*16;
        int ga3 = 3*192 + k*32 + ((m >> 3) & 1)*16;
        for (int cb = 0; cb < 4; ++cb){
            int c = cb*4 + grp;
            float re = (pm == c) ? 1.f : 0.f;   // P applied to basis column c
            float im = 0.f;
            gate_step<0>(re, im, gtab, ga0, 0);   gate_step<1>(re, im, gtab, ga1, 0);
            gate_step<2>(re, im, gtab, ga2, 0);   gate_step<3>(re, im, gtab, ga3, 0);
            re = bperm(bpaddr, re);
            im = bperm(bpaddr, im);
            gate_step<0>(re, im, gtab, ga0, 768); gate_step<1>(re, im, gtab, ga1, 768);
            gate_step<2>(re, im, gtab, ga2, 768); gate_step<3>(re, im, gtab, ga3, 768);
            float2* dst = (float2*)&ldsf[UBo + k*512 + m*32 + c*2];
            *dst = make_float2(re, im);
        }
    }
    __syncthreads();

    // ---------------- main layout: lane = (e, s) -----------------------------
    const int e = lane & 15;       // batch element (A/B/C col, A row)
    const int s = lane >> 4;       // slot: wire q for glue; k-quarter for frags
    const int sm1 = s & 1, sm2 = s >> 1;
    const bool sb0 = (s & 1) != 0, sb1 = (s & 2) != 0;
    const int addr32 = (lane ^ 32) * 4;

    // A-fragments of U_k (re/im): A_re[r][2c]=Re U, [2c+1]=-Im U; A_im: Im, Re
    F8 are[6], aim[6];
    #pragma unroll
    for (int k = 0; k < 6; ++k){
        const float* ub = &ldsf[UBo + k*512 + e*32 + s*8];
        float4 u01 = *(const float4*)ub;         // amps 4s, 4s+1 (re,im)
        float4 u23 = *(const float4*)(ub + 4);   // amps 4s+2, 4s+3
        are[k].h[0] = (f16x2){(f16)u01.x, (f16)(-u01.y)};
        are[k].h[1] = (f16x2){(f16)u01.z, (f16)(-u01.w)};
        are[k].h[2] = (f16x2){(f16)u23.x, (f16)(-u23.y)};
        are[k].h[3] = (f16x2){(f16)u23.z, (f16)(-u23.w)};
        aim[k].h[0] = (f16x2){(f16)u01.y, (f16)u01.x};
        aim[k].h[1] = (f16x2){(f16)u01.w, (f16)u01.z};
        aim[k].h[2] = (f16x2){(f16)u23.y, (f16)u23.x};
        aim[k].h[3] = (f16x2){(f16)u23.w, (f16)u23.z};
    }

    // A_z: rows 4q..4q+3 all = Wd column q  ->  z_q lands at lane (e, s=q), reg 0
    F8 az;
    #pragma unroll
    for (int j = 0; j < 4; ++j){
        int k0 = s*8 + 2*j, k1 = k0 + 1;
        float v0 = (k0 < 20) ? Wd[k0*20 + (e >> 2)] : 0.f;
        float v1 = (k1 < 20) ? Wd[k1*20 + (e >> 2)] : 0.f;
        az.h[j] = (f16x2){(f16)v0, (f16)v1};
    }
    const float bdv = bd[s];

    const int b0 = blockIdx.x * NELEM;
    const float* xp = x + (size_t)(b0 + e) * TSTEPS * NFEAT;

    const f32x4 z4 = {0.f, 0.f, 0.f, 0.f};
    f16x2 zh = pkrtz(0.f, 0.f);
    f16x2 hpk0 = zh, hpk1 = zh;
    float cst = 0.f, hval = 0.f;

    float4 xa = {0,0,0,0}, xb = {0,0,0,0};
    if (s < 2){
        xa = *(const float4*)(xp + s*8);
        xb = *(const float4*)(xp + s*8 + 4);
    }

    #pragma clang loop unroll(disable)
    for (int t = 0; t < TSTEPS; ++t){
        // ---- B_z = [x_t (k0..15) ; h (k16..19) ; 0] ----
        F8 bz;
        bool is2 = (s == 2);
        bz.h[0] = is2 ? hpk0 : pkrtz(xa.x, xa.y);
        bz.h[1] = is2 ? hpk1 : pkrtz(xa.z, xa.w);
        bz.h[2] = is2 ? zh   : pkrtz(xb.x, xb.y);
        bz.h[3] = is2 ? zh   : pkrtz(xb.z, xb.w);
        if (s == 3){ bz.h[0] = zh; bz.h[1] = zh; bz.h[2] = zh; bz.h[3] = zh; }
        f32x4 dz = __builtin_amdgcn_mfma_f32_16x16x32_f16(az.v, bz.v, z4, 0, 0, 0);

        if (s < 2 && t + 1 < TSTEPS){   // prefetch next x under the circuits
            xa = *(const float4*)(xp + (t+1)*NFEAT + s*8);
            xb = *(const float4*)(xp + (t+1)*NFEAT + s*8 + 4);
        }

        // ---- activations + init-state factors (64 lanes = 16 elems x 4 wires)
        float zval = dz[0] + bdv;
        float usel = 1.f - 2.f*frcp(__expf(zval) + 1.f);
        float c1, s1, c2, s2;
        half_cs(usel, c1, s1);
        half_cs(usel*usel, c2, s2);
        write_F(&ldsf[BCo], e, s, c1, s1, c2, s2);
        cfence();
        F8 bp;
        build_psi(&ldsf[BCo], e, sm1, sm2, bp);

        // ---- phase 1: f,i,Cg,o = 8 MFMAs + 4 ev extractions ----
        f32x4 dre[4], dim4[4];
        #pragma unroll
        for (int k = 0; k < 4; ++k){
            dre[k]  = __builtin_amdgcn_mfma_f32_16x16x32_f16(are[k].v, bp.v, z4, 0,0,0);
            dim4[k] = __builtin_amdgcn_mfma_f32_16x16x32_f16(aim[k].v, bp.v, z4, 0,0,0);
        }
        float evF = evs_own(dre[0], dim4[0], addr32, sb0, sb1);
        float evI = evs_own(dre[1], dim4[1], addr32, sb0, sb1);
        float evC = evs_own(dre[2], dim4[2], addr32, sb0, sb1);
        float evO = evs_own(dre[3], dim4[3], addr32, sb0, sb1);

        // ---- LSTM pointwise (full utilization) ----
        float fg = sigm(evF), ig = sigm(evI), Cg = sigm(evC), og = sigm(evO);
        cst = fg*cst + ig*Cg;
        float rs = og * tanh_f(cst);
        half_cs(rs, c1, s1);
        half_cs(rs*rs, c2, s2);
        write_F(&ldsf[BCo], e, s, c1, s1, c2, s2);
        cfence();
        F8 bp2;
        build_psi(&ldsf[BCo], e, sm1, sm2, bp2);

        // ---- phase 2: h (k=4), y (k=5) ----
        f32x4 hre = __builtin_amdgcn_mfma_f32_16x16x32_f16(are[4].v, bp2.v, z4, 0,0,0);
        f32x4 him = __builtin_amdgcn_mfma_f32_16x16x32_f16(aim[4].v, bp2.v, z4, 0,0,0);
        f32x4 yre = __builtin_amdgcn_mfma_f32_16x16x32_f16(are[5].v, bp2.v, z4, 0,0,0);
        f32x4 yim = __builtin_amdgcn_mfma_f32_16x16x32_f16(aim[5].v, bp2.v, z4, 0,0,0);
        hval = evs_own(hre, him, addr32, sb0, sb1);
        float yval = evs_own(yre, yim, addr32, sb0, sb1);

        // ---- y staging (coalesced flush every 4 steps) ----
        ldsf[YBo + e*20 + (t & 3)*4 + s] = yval;
        if ((t & 3) == 3){
            cfence();
            float4 y4 = *(const float4*)&ldsf[YBo + (lane >> 2)*20 + (lane & 3)*4];
            *(float4*)(out + (size_t)(b0 + (lane >> 2))*TSTEPS*4
                           + (size_t)(t - 3 + (lane & 3))*4) = y4;
        }

        // ---- h repack into next step's B_z fragment ----
        ldsf[HBo + e*4 + s] = hval;
        cfence();
        float4 h4 = *(const float4*)&ldsf[HBo + e*4];
        hpk0 = pkrtz(h4.x, h4.y);
        hpk1 = pkrtz(h4.z, h4.w);
    }

    // final c, h (one float per lane, full coverage)
    size_t cbase = (size_t)B * TSTEPS * 4;
    out[cbase + (size_t)(b0 + e)*4 + s] = cst;
    out[cbase + (size_t)B*4 + (size_t)(b0 + e)*4 + s] = hval;
}

extern "C" void kernel_launch(void* const* d_in, const int* in_sizes, int n_in,
                              void* d_out, int out_size, void* d_ws, size_t ws_size,
                              hipStream_t stream) {
    const float* x   = (const float*)d_in[0];
    const float* phi = (const float*)d_in[1];
    const float* Wd  = (const float*)d_in[2];
    const float* bd  = (const float*)d_in[3];
    float* out = (float*)d_out;
    int B = in_sizes[0] / (TSTEPS * NFEAT);   // 4096
    int blocks = B / NELEM;                   // 256 blocks x 1 wave x 16 elems
    hipLaunchKernelGGL(qlstm_kernel, dim3(blocks), dim3(64), 0, stream,
                       x, phi, Wd, bd, out, B);
}

// Round 8
// 153.535 us; speedup vs baseline: 4.3547x; 1.1548x over previous
//
#include <hip/hip_runtime.h>
#include <math.h>

#define TSTEPS 128
#define NFEAT 16
#define NELEM 16   // batch elements per wave

typedef __fp16 f16;
typedef __fp16 f16x2 __attribute__((ext_vector_type(2)));
typedef __fp16 f16x8 __attribute__((ext_vector_type(8)));
typedef float f32x4 __attribute__((ext_vector_type(4)));

union F8 { f16x8 v; f16x2 h[4]; };

__device__ __forceinline__ float frcp(float x){ return __builtin_amdgcn_rcpf(x); }
__device__ __forceinline__ float frsq(float x){ return __builtin_amdgcn_rsqf(x); }
__device__ __forceinline__ float bperm(int addr, float v){
    return __int_as_float(__builtin_amdgcn_ds_bpermute(addr, __float_as_int(v)));
}
__device__ __forceinline__ f16x2 pkrtz(float a, float b){
    return __builtin_amdgcn_cvt_pkrtz(a, b);
}
__device__ __forceinline__ float dpp_xor1(float v){
    return __int_as_float(__builtin_amdgcn_update_dpp(0, __float_as_int(v), 0xB1, 0xF, 0xF, true));
}
__device__ __forceinline__ float dpp_xor2(float v){
    return __int_as_float(__builtin_amdgcn_update_dpp(0, __float_as_int(v), 0x4E, 0xF, 0xF, true));
}
__device__ __forceinline__ float swz_xor4(float v){
    return __int_as_float(__builtin_amdgcn_ds_swizzle(__float_as_int(v), 0x101F));
}
__device__ __forceinline__ float swz_xor8(float v){
    return __int_as_float(__builtin_amdgcn_ds_swizzle(__float_as_int(v), 0x201F));
}
template<int MASK> __device__ __forceinline__ float pshfl(float v){
    if constexpr (MASK == 1) return dpp_xor1(v);
    else if constexpr (MASK == 2) return dpp_xor2(v);
    else if constexpr (MASK == 4) return swz_xor4(v);
    else return swz_xor8(v);
}
__device__ __forceinline__ void cfence(){ __asm__ __volatile__("" ::: "memory"); }

__device__ __forceinline__ float sigm(float x){ return frcp(1.f + __expf(-x)); }
__device__ __forceinline__ float tanh_f(float x){ return 1.f - 2.f * frcp(__expf(2.f*x) + 1.f); }

// c = cos(atan(u)/2), s = sin(atan(u)/2)
__device__ __forceinline__ void half_cs(float u, float &c, float &s){
    float ca = frsq(1.f + u*u);
    float x  = (1.f + ca) * 0.5f;
    float t  = frsq(x);
    c = x * t;
    s = u * ca * 0.5f * t;
}

// merged RZ*RY*RX on wire I (prologue / U-construction only)
template<int I>
__device__ __forceinline__ void gate_step(float &re, float &im,
                                          const float* gt, int ai, int loff){
    const float4 g = *(const float4*)((const char*)gt + ai + loff);
    float pre = pshfl<(1 << I)>(re);
    float pim = pshfl<(1 << I)>(im);
    float nre = g.x*re - g.y*im + g.z*pre - g.w*pim;
    float nim = g.x*im + g.y*re + g.z*pim + g.w*pre;
    re = nre; im = nim;
}

// lane (e,s) emits complex factors F_s(0), F_s(1) of its wire into LDS
__device__ __forceinline__ void write_F(float* bc, int e, int s,
                                        float c1, float s1, float c2, float s2){
    float4 w;
    w.x = c1 * c2;  w.y = -(c1 * s2);    // F(0)
    w.z = s1 * c2;  w.w = s1 * s2;       // F(1)
    *(float4*)(bc + e*20 + s*4) = w;
}

// lane (e,s) builds its 4 amplitudes a=4s..4s+3 of elem e's init state (B-fragment)
__device__ __forceinline__ void build_psi(const float* bc, int e, int sm1, int sm2,
                                          F8 &bp){
    const float4 w0 = *(const float4*)(bc + e*20);               // wire0: F(0),F(1)
    const float4 w1 = *(const float4*)(bc + e*20 + 4);           // wire1
    const float2 F2 = *(const float2*)(bc + e*20 + 8  + sm1*2);  // F_2(s&1)
    const float2 F3 = *(const float2*)(bc + e*20 + 12 + sm2*2);  // F_3(s>>1)
    float pr = F2.x*F3.x - F2.y*F3.y;
    float pi = F2.x*F3.y + F2.y*F3.x;                            // prefix
    float P0r = pr*w1.x - pi*w1.y, P0i = pr*w1.y + pi*w1.x;      // prefix*F1(0)
    float P1r = pr*w1.z - pi*w1.w, P1i = pr*w1.w + pi*w1.z;      // prefix*F1(1)
    float a0r = P0r*w0.x - P0i*w0.y, a0i = P0r*w0.y + P0i*w0.x;
    float a1r = P0r*w0.z - P0i*w0.w, a1i = P0r*w0.w + P0i*w0.z;
    float a2r = P1r*w0.x - P1i*w0.y, a2i = P1r*w0.y + P1i*w0.x;
    float a3r = P1r*w0.z - P1i*w0.w, a3i = P1r*w0.w + P1i*w0.z;
    bp.h[0] = pkrtz(a0r, a0i);
    bp.h[1] = pkrtz(a1r, a1i);
    bp.h[2] = pkrtz(a2r, a2i);
    bp.h[3] = pkrtz(a3r, a3i);
}

// pack two circuits' probabilities into the EV-MFMA B-fragment:
// k-slot 8s+j <-> amp 4s+(j&3); j<4 = even circuit, j>=4 = odd circuit
__device__ __forceinline__ F8 pack_P(const f32x4 &reE, const f32x4 &imE,
                                     const f32x4 &reO, const f32x4 &imO){
    F8 b;
    b.h[0] = pkrtz(reE[0]*reE[0] + imE[0]*imE[0], reE[1]*reE[1] + imE[1]*imE[1]);
    b.h[1] = pkrtz(reE[2]*reE[2] + imE[2]*imE[2], reE[3]*reE[3] + imE[3]*imE[3]);
    b.h[2] = pkrtz(reO[0]*reO[0] + imO[0]*imO[0], reO[1]*reO[1] + imO[1]*imO[1]);
    b.h[3] = pkrtz(reO[2]*reO[2] + imO[2]*imO[2], reO[3]*reO[3] + imO[3]*imO[3]);
    return b;
}

__global__ void __launch_bounds__(64, 1) qlstm_kernel(
    const float* __restrict__ x, const float* __restrict__ phi,
    const float* __restrict__ Wd, const float* __restrict__ bd,
    float* __restrict__ out, int B)
{
    // gtab: 8 rows (l,i) x 48 floats (12 entries x {Ar,Ai,Br,Bi}) -- 192B stride
    __shared__ __align__(16) float gtab[384];
    __shared__ __align__(16) float ldsf[3776];
    const int UBo = 0;      // 3072 floats: U[k][m][c] complex at k*512+m*32+c*2
    const int BCo = 3072;   // 16 elems x 20 floats: factor pairs
    const int YBo = 3392;   // 16 elems x 20 floats: y staging (4 steps)
    const int HBo = 3712;   // 16 elems x 4 floats: h transpose

    const int tid  = threadIdx.x;
    const int lane = tid & 63;
    const int m    = lane & 15;
    const int grp  = lane >> 4;

    // ---------------- prologue: merged-gate table ------
    for (int idx = tid; idx < 96; idx += 64){
        int i = idx & 3, l = (idx >> 2) & 1, bb = (idx >> 3) & 1, k = idx >> 4;
        const float* pp = phi + (k*2 + l)*12 + 3*i;
        float ca, sa, cb, sb, cg, sg;
        __sincosf(0.5f*pp[0], &sa, &ca);
        __sincosf(0.5f*pp[1], &sb, &cb);
        __sincosf(0.5f*pp[2], &sg, &cg);
        float Ar, Ai, Br, Bi;
        if (bb == 0){
            float m00r = cb*ca,  m00i = sb*sa;
            float m01r = -sb*ca, m01i = -cb*sa;
            Ar = m00r*cg + m00i*sg;  Ai = m00i*cg - m00r*sg;
            Br = m01r*cg + m01i*sg;  Bi = m01i*cg - m01r*sg;
        } else {
            float m10r = sb*ca, m10i = -cb*sa;
            float m11r = cb*ca, m11i = -sb*sa;
            Ar = m11r*cg - m11i*sg;  Ai = m11i*cg + m11r*sg;
            Br = m10r*cg - m10i*sg;  Bi = m10i*cg + m10r*sg;
        }
        float* dst = gtab + (l*4 + i)*48 + (k*2 + bb)*4;
        dst[0] = Ar; dst[1] = Ai; dst[2] = Br; dst[3] = Bi;
    }
    __syncthreads();

    // CNOT-block permutation P^{-1}(m) and mid-circuit bpermute address
    const int n0 = m & 1, n1 = (m >> 1) & 1, n2 = (m >> 2) & 1, n3 = (m >> 3) & 1;
    const int pm = (n0^n1^n2) | ((n0^n2^n3) << 1) | ((n0^n1^n3) << 2) | ((n0^n1) << 3);
    const int bpaddr = ((lane & 48) | pm) * 4;

    // ---------------- prologue: build U_k columns via shuffle circuit --------
    for (int k = 0; k < 6; ++k){
        int ga0 = 0*192 + k*32 + ((m >> 0) & 1)*16;
        int ga1 = 1*192 + k*32 + ((m >> 1) & 1)*16;
        int ga2 = 2*192 + k*32 + ((m >> 2) & 1)*16;
        int ga3 = 3*192 + k*32 + ((m >> 3) & 1)*16;
        for (int cb = 0; cb < 4; ++cb){
            int c = cb*4 + grp;
            float re = (pm == c) ? 1.f : 0.f;   // P applied to basis column c
            float im = 0.f;
            gate_step<0>(re, im, gtab, ga0, 0);   gate_step<1>(re, im, gtab, ga1, 0);
            gate_step<2>(re, im, gtab, ga2, 0);   gate_step<3>(re, im, gtab, ga3, 0);
            re = bperm(bpaddr, re);
            im = bperm(bpaddr, im);
            gate_step<0>(re, im, gtab, ga0, 768); gate_step<1>(re, im, gtab, ga1, 768);
            gate_step<2>(re, im, gtab, ga2, 768); gate_step<3>(re, im, gtab, ga3, 768);
            float2* dst = (float2*)&ldsf[UBo + k*512 + m*32 + c*2];
            *dst = make_float2(re, im);
        }
    }
    __syncthreads();

    // ---------------- main layout: lane = (e, s) -----------------------------
    const int e = lane & 15;       // batch element (A/B/C col, A row)
    const int s = lane >> 4;       // slot: wire q for glue; k-quarter for frags
    const int sm1 = s & 1, sm2 = s >> 1;

    // A-fragments of U_k (re/im): A_re[r][2c]=Re U, [2c+1]=-Im U; A_im: Im, Re
    F8 are[6], aim[6];
    #pragma unroll
    for (int k = 0; k < 6; ++k){
        const float* ub = &ldsf[UBo + k*512 + e*32 + s*8];
        float4 u01 = *(const float4*)ub;         // amps 4s, 4s+1 (re,im)
        float4 u23 = *(const float4*)(ub + 4);   // amps 4s+2, 4s+3
        are[k].h[0] = (f16x2){(f16)u01.x, (f16)(-u01.y)};
        are[k].h[1] = (f16x2){(f16)u01.z, (f16)(-u01.w)};
        are[k].h[2] = (f16x2){(f16)u23.x, (f16)(-u23.y)};
        are[k].h[3] = (f16x2){(f16)u23.z, (f16)(-u23.w)};
        aim[k].h[0] = (f16x2){(f16)u01.y, (f16)u01.x};
        aim[k].h[1] = (f16x2){(f16)u01.w, (f16)u01.z};
        aim[k].h[2] = (f16x2){(f16)u23.y, (f16)u23.x};
        aim[k].h[3] = (f16x2){(f16)u23.w, (f16)u23.z};
    }

    // A_sign fragment (constant): EV = A_sign @ P.
    // A_sign[i][8s'+j] = (i&3)<2 ? (j<4 ? sgn(i>>2, 4s'+j) : 0)
    //                            : (j>=4 ? sgn(i>>2, 4s'+(j-4)) : 0)
    // -> lane (e,s) output regs: 0,1 = ev_s(even circuit); 2,3 = ev_s(odd)
    F8 asig;
    {
        int q = e >> 2;
        bool evenrows = (e & 3) < 2;
        #pragma unroll
        for (int j = 0; j < 8; ++j){
            int amp = 4*s + (j & 3);
            float v = 0.f;
            if (evenrows == (j < 4))
                v = ((amp >> q) & 1) ? -1.f : 1.f;
            asig.v[j] = (f16)v;
        }
    }

    // A_z: rows 4q..4q+3 all = Wd column q  ->  z_q lands at lane (e, s=q), reg 0
    F8 az;
    #pragma unroll
    for (int j = 0; j < 4; ++j){
        int k0 = s*8 + 2*j, k1 = k0 + 1;
        float v0 = (k0 < 20) ? Wd[k0*20 + (e >> 2)] : 0.f;
        float v1 = (k1 < 20) ? Wd[k1*20 + (e >> 2)] : 0.f;
        az.h[j] = (f16x2){(f16)v0, (f16)v1};
    }
    const float bdv = bd[s];

    const int b0 = blockIdx.x * NELEM;
    const float* xp = x + (size_t)(b0 + e) * TSTEPS * NFEAT;

    const f32x4 z4 = {0.f, 0.f, 0.f, 0.f};
    f16x2 zh = pkrtz(0.f, 0.f);
    f16x2 hpk0 = zh, hpk1 = zh;
    float cst = 0.f, hval = 0.f;

    float4 xa = {0,0,0,0}, xb = {0,0,0,0};
    if (s < 2){
        xa = *(const float4*)(xp + s*8);
        xb = *(const float4*)(xp + s*8 + 4);
    }

    #pragma clang loop unroll(disable)
    for (int t = 0; t < TSTEPS; ++t){
        // ---- B_z = [x_t (k0..15) ; h (k16..19) ; 0] ----
        F8 bz;
        bool is2 = (s == 2);
        bz.h[0] = is2 ? hpk0 : pkrtz(xa.x, xa.y);
        bz.h[1] = is2 ? hpk1 : pkrtz(xa.z, xa.w);
        bz.h[2] = is2 ? zh   : pkrtz(xb.x, xb.y);
        bz.h[3] = is2 ? zh   : pkrtz(xb.z, xb.w);
        if (s == 3){ bz.h[0] = zh; bz.h[1] = zh; bz.h[2] = zh; bz.h[3] = zh; }
        f32x4 dz = __builtin_amdgcn_mfma_f32_16x16x32_f16(az.v, bz.v, z4, 0, 0, 0);

        if (s < 2 && t + 1 < TSTEPS){   // prefetch next x under the circuits
            xa = *(const float4*)(xp + (t+1)*NFEAT + s*8);
            xb = *(const float4*)(xp + (t+1)*NFEAT + s*8 + 4);
        }

        // ---- activations + init-state factors (64 lanes = 16 elems x 4 wires)
        float zval = dz[0] + bdv;
        float usel = 1.f - 2.f*frcp(__expf(zval) + 1.f);
        float c1, s1, c2, s2;
        half_cs(usel, c1, s1);
        half_cs(usel*usel, c2, s2);
        write_F(&ldsf[BCo], e, s, c1, s1, c2, s2);
        cfence();
        F8 bp;
        build_psi(&ldsf[BCo], e, sm1, sm2, bp);

        // ---- phase 1: f,i,Cg,o = 8 U-MFMAs + 2 EV-MFMAs ----
        f32x4 dre[4], dim4[4];
        #pragma unroll
        for (int k = 0; k < 4; ++k){
            dre[k]  = __builtin_amdgcn_mfma_f32_16x16x32_f16(are[k].v, bp.v, z4, 0,0,0);
            dim4[k] = __builtin_amdgcn_mfma_f32_16x16x32_f16(aim[k].v, bp.v, z4, 0,0,0);
        }
        F8 bp1 = pack_P(dre[0], dim4[0], dre[1], dim4[1]);   // f (even), i (odd)
        F8 bp2 = pack_P(dre[2], dim4[2], dre[3], dim4[3]);   // Cg, o
        f32x4 ev1 = __builtin_amdgcn_mfma_f32_16x16x32_f16(asig.v, bp1.v, z4, 0,0,0);
        f32x4 ev2 = __builtin_amdgcn_mfma_f32_16x16x32_f16(asig.v, bp2.v, z4, 0,0,0);

        // ---- LSTM pointwise (full utilization) ----
        float fg = sigm(ev1[0]), ig = sigm(ev1[2]), Cg = sigm(ev2[0]), og = sigm(ev2[2]);
        cst = fg*cst + ig*Cg;
        float rs = og * tanh_f(cst);
        half_cs(rs, c1, s1);
        half_cs(rs*rs, c2, s2);
        write_F(&ldsf[BCo], e, s, c1, s1, c2, s2);
        cfence();
        F8 bpp;
        build_psi(&ldsf[BCo], e, sm1, sm2, bpp);

        // ---- phase 2: h (k=4), y (k=5) = 4 U-MFMAs + 1 EV-MFMA ----
        f32x4 hre = __builtin_amdgcn_mfma_f32_16x16x32_f16(are[4].v, bpp.v, z4, 0,0,0);
        f32x4 him = __builtin_amdgcn_mfma_f32_16x16x32_f16(aim[4].v, bpp.v, z4, 0,0,0);
        f32x4 yre = __builtin_amdgcn_mfma_f32_16x16x32_f16(are[5].v, bpp.v, z4, 0,0,0);
        f32x4 yim = __builtin_amdgcn_mfma_f32_16x16x32_f16(aim[5].v, bpp.v, z4, 0,0,0);
        F8 bph = pack_P(hre, him, yre, yim);                 // h (even), y (odd)
        f32x4 evh = __builtin_amdgcn_mfma_f32_16x16x32_f16(asig.v, bph.v, z4, 0,0,0);
        hval = evh[0];
        float yval = evh[2];

        // ---- y staging (coalesced flush every 4 steps) ----
        ldsf[YBo + e*20 + (t & 3)*4 + s] = yval;
        if ((t & 3) == 3){
            cfence();
            float4 y4 = *(const float4*)&ldsf[YBo + (lane >> 2)*20 + (lane & 3)*4];
            *(float4*)(out + (size_t)(b0 + (lane >> 2))*TSTEPS*4
                           + (size_t)(t - 3 + (lane & 3))*4) = y4;
        }

        // ---- h repack into next step's B_z fragment ----
        ldsf[HBo + e*4 + s] = hval;
        cfence();
        float4 h4 = *(const float4*)&ldsf[HBo + e*4];
        hpk0 = pkrtz(h4.x, h4.y);
        hpk1 = pkrtz(h4.z, h4.w);
    }

    // final c, h (one float per lane, full coverage)
    size_t cbase = (size_t)B * TSTEPS * 4;
    out[cbase + (size_t)(b0 + e)*4 + s] = cst;
    out[cbase + (size_t)B*4 + (size_t)(b0 + e)*4 + s] = hval;
}

extern "C" void kernel_launch(void* const* d_in, const int* in_sizes, int n_in,
                              void* d_out, int out_size, void* d_ws, size_t ws_size,
                              hipStream_t stream) {
    const float* x   = (const float*)d_in[0];
    const float* phi = (const float*)d_in[1];
    const float* Wd  = (const float*)d_in[2];
    const float* bd  = (const float*)d_in[3];
    float* out = (float*)d_out;
    int B = in_sizes[0] / (TSTEPS * NFEAT);   // 4096
    int blocks = B / NELEM;                   // 256 blocks x 1 wave x 16 elems
    hipLaunchKernelGGL(qlstm_kernel, dim3(blocks), dim3(64), 0, stream,
                       x, phi, Wd, bd, out, B);
}